// Round 4
// baseline (107.537 us; speedup 1.0000x reference)
//
#include <hip/hip_runtime.h>
#include <hip/hip_cooperative_groups.h>

namespace cg = cooperative_groups;

#define NN 4096
#define CAP 256
#define THRV 0.99f

typedef __attribute__((ext_vector_type(8))) short short8v;
typedef __attribute__((ext_vector_type(4))) float f32x4;

__device__ inline unsigned short f2bf(float f) {
  unsigned u = __builtin_bit_cast(unsigned, f);
  u = (u + 0x7fffu + ((u >> 16) & 1u)) >> 16;   // RNE
  return (unsigned short)u;
}
__device__ inline unsigned pkmax(unsigned a, unsigned b) {
  unsigned r;
  asm("v_pk_max_u16 %0, %1, %2" : "=v"(r) : "v"(a), "v"(b));
  return r;
}
__device__ inline uint4 max4(uint4 a, uint4 b) {
  return make_uint4(pkmax(a.x, b.x), pkmax(a.y, b.y), pkmax(a.z, b.z), pkmax(a.w, b.w));
}

// Packed fragment layout for bf16 weights: frag(ktIdx,nf) is 512 bf16 (1KB),
// lane = g*16 + (n&15) holds 8 contiguous u16: elem = (k&3) + 4*((k>>4)&1),
// g = (k>>2)&3.  One uint4/lane per MFMA B-frag.

__global__ __launch_bounds__(512) void fused_all(
    const float* __restrict__ x, const float* __restrict__ A,
    const float* __restrict__ Wp0, const float* __restrict__ bp0,
    const float* __restrict__ Ws0, const float* __restrict__ bs0,
    const float* __restrict__ Wn0, const float* __restrict__ bn0,
    const float* __restrict__ Wp1, const float* __restrict__ bp1,
    const float* __restrict__ Ws1, const float* __restrict__ bs1,
    const float* __restrict__ Wn1, const float* __restrict__ bn1,
    unsigned short* __restrict__ tWn0, unsigned short* __restrict__ tWp1,
    unsigned short* __restrict__ tWs1, unsigned short* __restrict__ tWn1,
    unsigned short* __restrict__ scores0, unsigned short* __restrict__ scores1,
    float* __restrict__ out) {
  cg::grid_group grid = cg::this_grid();

  __shared__ int scnt[16];
  __shared__ unsigned short snb[16][CAP];
  __shared__ unsigned short pool2[16][2][136];
  __shared__ unsigned short pooled[16][136];
  __shared__ unsigned short xb[16][264];
  __shared__ float Sblk[16][132];
  __shared__ float ssqs[16];
  __shared__ float ssqw[4][16];

  const int tid = threadIdx.x;
  const int wv = tid >> 6, lane = tid & 63, g = lane >> 4, r15 = lane & 15;
  const int r0 = blockIdx.x * 16;

  if (tid < 16) scnt[tid] = 0;
  __syncthreads();

  // ================= PHASE 1: A-scan (waves 0-3) || prep + L0 GEMM (waves 4-7) ====
  if (tid < 256) {
    const float4* Ar = (const float4*)(A + (size_t)r0 * NN);
    float4 v0 = Ar[tid], v1 = Ar[tid + 256], v2 = Ar[tid + 512], v3 = Ar[tid + 768];
    for (int r = 0; r < 16; ++r) {
      float4 n0, n1, n2, n3;
      if (r < 15) {
        const float4* An = (const float4*)(A + (size_t)(r0 + r + 1) * NN);
        n0 = An[tid]; n1 = An[tid + 256]; n2 = An[tid + 512]; n3 = An[tid + 768];
      }
      int* c = &scnt[r];
      auto proc = [&](float4 v, int j) {
        if (v.x > THRV) { int p = atomicAdd(c, 1); if (p < CAP) snb[r][p] = (unsigned short)j; }
        if (v.y > THRV) { int p = atomicAdd(c, 1); if (p < CAP) snb[r][p] = (unsigned short)(j + 1); }
        if (v.z > THRV) { int p = atomicAdd(c, 1); if (p < CAP) snb[r][p] = (unsigned short)(j + 2); }
        if (v.w > THRV) { int p = atomicAdd(c, 1); if (p < CAP) snb[r][p] = (unsigned short)(j + 3); }
      };
      proc(v0, 4 * tid); proc(v1, 4 * (tid + 256));
      proc(v2, 4 * (tid + 512)); proc(v3, 4 * (tid + 768));
      v0 = n0; v1 = n1; v2 = n2; v3 = n3;
    }
  } else {
    const int t2 = tid - 256;
    // ---- distributed weight prep (blocks 0..95 only) ----
    if (blockIdx.x < 96) {
      int id = blockIdx.x;
      const float* src; unsigned short* dst; int base;
      if (id < 16)      { src = Wn0; dst = tWn0; base = id; }
      else if (id < 48) { src = Wp1; dst = tWp1; base = id - 16; }
      else if (id < 80) { src = Ws1; dst = tWs1; base = id - 48; }
      else              { src = Wn1; dst = tWn1; base = id - 80; }
      int e0 = base * 1024 + t2 * 4;
      float4 v = *(const float4*)(src + e0);
      int k = e0 >> 7, n = e0 & 127;
      float vv[4] = {v.x, v.y, v.z, v.w};
      int elem = (k & 3) + 4 * ((k >> 4) & 1);
      int gg = (k >> 2) & 3;
      int fragkt = (k >> 5) * 8;
#pragma unroll
      for (int i = 0; i < 4; ++i) {
        int nn = n + i;
        int idx = ((fragkt + (nn >> 4)) << 9) + ((gg * 16 + (nn & 15)) << 3) + elem;
        dst[idx] = f2bf(vv[i]);
      }
    }
    // ---- L0 dual GEMM (f32 weights direct, in-reg cvt) ----
    const int w4 = wv - 4;            // 0..3
    const int set = w4 >> 1;          // 0: Wp0->scores0, 1: Ws0->Sblk
    const int nfb = (w4 & 1) * 4;
    const float* W = set ? Ws0 : Wp0;
    const float* bias = set ? bs0 : bp0;
    const int row = r0 + r15;
    f32x4 acc[4] = {};
    for (int kt = 0; kt < 256; kt += 32) {
      const float* xp = x + (size_t)row * 256 + kt + 4 * g;
      float4 lo = *(const float4*)xp;
      float4 hi = *(const float4*)(xp + 16);
      short8v a;
      a[0] = (short)f2bf(lo.x); a[1] = (short)f2bf(lo.y);
      a[2] = (short)f2bf(lo.z); a[3] = (short)f2bf(lo.w);
      a[4] = (short)f2bf(hi.x); a[5] = (short)f2bf(hi.y);
      a[6] = (short)f2bf(hi.z); a[7] = (short)f2bf(hi.w);
#pragma unroll
      for (int f = 0; f < 4; ++f) {
        int nf = nfb + f;
        const float* wp = W + (size_t)(kt + 4 * g) * 128 + nf * 16 + r15;
        short8v b;
#pragma unroll
        for (int j = 0; j < 4; ++j) b[j] = (short)f2bf(wp[(size_t)j * 128]);
#pragma unroll
        for (int j = 0; j < 4; ++j) b[4 + j] = (short)f2bf(wp[(size_t)(16 + j) * 128]);
        acc[f] = __builtin_amdgcn_mfma_f32_16x16x32_bf16(a, b, acc[f], 0, 0, 0);
      }
    }
#pragma unroll
    for (int f = 0; f < 4; ++f) {
      int col = (nfb + f) * 16 + r15;
      float bv = bias[col];
#pragma unroll
      for (int rr = 0; rr < 4; ++rr) {
        int lr = 4 * g + rr;
        float t = acc[f][rr] + bv;
        if (set == 0) scores0[(size_t)(r0 + lr) * 128 + col] = f2bf(fmaxf(t, 0.f));
        else          Sblk[lr][col] = t;
      }
    }
  }
  grid.sync();

  // ================= PHASE 2: gather -> pool GEMM || self -> norm -> L1 GEMM =====
  {
    // gather-max from scores0, 2-way neighbor split, unrolled
    const int r = tid >> 5, sub = tid & 31;
    const int h = sub >> 4, c8 = (sub & 15) * 8;
    const int c = min(scnt[r], CAP);
    uint4 m0 = make_uint4(0, 0, 0, 0), m1 = make_uint4(0, 0, 0, 0);
    int k = h;
    for (; k + 2 < c; k += 4) {
      int j0 = snb[r][k], j1 = snb[r][k + 2];
      uint4 a0 = *(const uint4*)(scores0 + (size_t)j0 * 128 + c8);
      uint4 a1 = *(const uint4*)(scores0 + (size_t)j1 * 128 + c8);
      m0 = max4(m0, a0); m1 = max4(m1, a1);
    }
    for (; k < c; k += 2)
      m0 = max4(m0, *(const uint4*)(scores0 + (size_t)snb[r][k] * 128 + c8));
    *(uint4*)&pool2[r][h][c8] = max4(m0, m1);
  }
  __syncthreads();
  if (tid < 256) {
    const int r = tid >> 4, c8 = (tid & 15) * 8;
    uint4 a = *(const uint4*)&pool2[r][0][c8];
    uint4 b = *(const uint4*)&pool2[r][1][c8];
    *(uint4*)&pooled[r][c8] = max4(a, b);
  }
  __syncthreads();

  float sv[8];
  f32x4 pacc[2] = {};
  const int srow = tid >> 4, sc8 = (tid & 15) * 8;
  if (tid < 256) {
    // self half from Sblk (S0)
    float4 sa = *(const float4*)&Sblk[srow][sc8];
    float4 sb = *(const float4*)&Sblk[srow][sc8 + 4];
    sv[0] = fmaxf(sa.x, 0.f); sv[1] = fmaxf(sa.y, 0.f);
    sv[2] = fmaxf(sa.z, 0.f); sv[3] = fmaxf(sa.w, 0.f);
    sv[4] = fmaxf(sb.x, 0.f); sv[5] = fmaxf(sb.y, 0.f);
    sv[6] = fmaxf(sb.z, 0.f); sv[7] = fmaxf(sb.w, 0.f);
    float ps = 0.f;
#pragma unroll
    for (int i = 0; i < 8; ++i) ps += sv[i] * sv[i];
#pragma unroll
    for (int off = 1; off < 16; off <<= 1) ps += __shfl_xor(ps, off, 16);
    if ((tid & 15) == 0) ssqs[srow] = ps;
  } else {
    // pool GEMM: pooled[16x128] @ tWn0, wave wv2 owns nf {2wv2, 2wv2+1}
    const int wv2 = wv - 4;
#pragma unroll
    for (int kt = 0; kt < 128; kt += 32) {
      ushort4 alo = *(const ushort4*)&pooled[r15][kt + 4 * g];
      ushort4 ahi = *(const ushort4*)&pooled[r15][kt + 16 + 4 * g];
      short8v a;
      a[0] = alo.x; a[1] = alo.y; a[2] = alo.z; a[3] = alo.w;
      a[4] = ahi.x; a[5] = ahi.y; a[6] = ahi.z; a[7] = ahi.w;
#pragma unroll
      for (int f = 0; f < 2; ++f) {
        uint4 bw = *((const uint4*)(tWn0 + (size_t)((kt >> 5) * 8 + 2 * wv2 + f) * 512) + lane);
        pacc[f] = __builtin_amdgcn_mfma_f32_16x16x32_bf16(a, __builtin_bit_cast(short8v, bw), pacc[f], 0, 0, 0);
      }
    }
#pragma unroll
    for (int f = 0; f < 2; ++f) {
      float bv = bn0[(2 * wv2 + f) * 16 + r15];
#pragma unroll
      for (int rr = 0; rr < 4; ++rr) pacc[f][rr] = fmaxf(pacc[f][rr] + bv, 0.f);
    }
#pragma unroll
    for (int rr = 0; rr < 4; ++rr) {
      float ps = pacc[0][rr] * pacc[0][rr] + pacc[1][rr] * pacc[1][rr];
#pragma unroll
      for (int off = 1; off < 16; off <<= 1) ps += __shfl_xor(ps, off, 16);
      if (r15 == 0) ssqw[wv2][4 * g + rr] = ps;
    }
  }
  __syncthreads();

  if (tid < 256) {
    float tot = ssqs[srow] + ssqw[0][srow] + ssqw[1][srow] + ssqw[2][srow] + ssqw[3][srow];
    float sc = 1.f / fmaxf(sqrtf(tot), 1e-12f);
    unsigned short hh[8];
#pragma unroll
    for (int i = 0; i < 8; ++i) hh[i] = f2bf(sv[i] * sc);
    uint4 wvv;
    wvv.x = (unsigned)hh[0] | ((unsigned)hh[1] << 16);
    wvv.y = (unsigned)hh[2] | ((unsigned)hh[3] << 16);
    wvv.z = (unsigned)hh[4] | ((unsigned)hh[5] << 16);
    wvv.w = (unsigned)hh[6] | ((unsigned)hh[7] << 16);
    *(uint4*)&xb[srow][sc8] = wvv;
  } else {
    const int wv2 = wv - 4;
#pragma unroll
    for (int rr = 0; rr < 4; ++rr) {
      int row = 4 * g + rr;
      float tot = ssqs[row] + ssqw[0][row] + ssqw[1][row] + ssqw[2][row] + ssqw[3][row];
      float sc = 1.f / fmaxf(sqrtf(tot), 1e-12f);
#pragma unroll
      for (int f = 0; f < 2; ++f)
        xb[row][128 + (2 * wv2 + f) * 16 + r15] = f2bf(pacc[f][rr] * sc);
    }
  }
  __syncthreads();

  // L1 dual GEMM on xb[16][256]: 8 waves, 2 frags each
  {
    const int s = wv >> 2;
    const unsigned short* Wt = s ? tWs1 : tWp1;
    const float* bb = s ? bs1 : bp1;
    const int nf0 = (wv & 3) * 2;
    f32x4 dacc[2] = {};
#pragma unroll
    for (int kt = 0; kt < 256; kt += 32) {
      ushort4 alo = *(const ushort4*)&xb[r15][kt + 4 * g];
      ushort4 ahi = *(const ushort4*)&xb[r15][kt + 16 + 4 * g];
      short8v a;
      a[0] = alo.x; a[1] = alo.y; a[2] = alo.z; a[3] = alo.w;
      a[4] = ahi.x; a[5] = ahi.y; a[6] = ahi.z; a[7] = ahi.w;
#pragma unroll
      for (int f = 0; f < 2; ++f) {
        uint4 bw = *((const uint4*)(Wt + (size_t)((kt >> 5) * 8 + nf0 + f) * 512) + lane);
        dacc[f] = __builtin_amdgcn_mfma_f32_16x16x32_bf16(a, __builtin_bit_cast(short8v, bw), dacc[f], 0, 0, 0);
      }
    }
#pragma unroll
    for (int f = 0; f < 2; ++f) {
      int col = (nf0 + f) * 16 + r15;
      float bv = bb[col];
#pragma unroll
      for (int rr = 0; rr < 4; ++rr) {
        int lr = 4 * g + rr;
        float t = dacc[f][rr] + bv;
        if (s == 0) scores1[(size_t)(r0 + lr) * 128 + col] = f2bf(fmaxf(t, 0.f));
        else        Sblk[lr][col] = t;
      }
    }
  }
  grid.sync();

  // ================= PHASE 3: gather -> pool GEMM || self -> norm -> out =========
  {
    const int r = tid >> 5, sub = tid & 31;
    const int h = sub >> 4, c8 = (sub & 15) * 8;
    const int c = min(scnt[r], CAP);
    uint4 m0 = make_uint4(0, 0, 0, 0), m1 = make_uint4(0, 0, 0, 0);
    int k = h;
    for (; k + 2 < c; k += 4) {
      int j0 = snb[r][k], j1 = snb[r][k + 2];
      uint4 a0 = *(const uint4*)(scores1 + (size_t)j0 * 128 + c8);
      uint4 a1 = *(const uint4*)(scores1 + (size_t)j1 * 128 + c8);
      m0 = max4(m0, a0); m1 = max4(m1, a1);
    }
    for (; k < c; k += 2)
      m0 = max4(m0, *(const uint4*)(scores1 + (size_t)snb[r][k] * 128 + c8));
    *(uint4*)&pool2[r][h][c8] = max4(m0, m1);
  }
  __syncthreads();
  if (tid < 256) {
    const int r = tid >> 4, c8 = (tid & 15) * 8;
    uint4 a = *(const uint4*)&pool2[r][0][c8];
    uint4 b = *(const uint4*)&pool2[r][1][c8];
    *(uint4*)&pooled[r][c8] = max4(a, b);
  }
  __syncthreads();

  f32x4 qacc[2] = {};
  if (tid < 256) {
    float4 sa = *(const float4*)&Sblk[srow][sc8];
    float4 sb = *(const float4*)&Sblk[srow][sc8 + 4];
    sv[0] = fmaxf(sa.x, 0.f); sv[1] = fmaxf(sa.y, 0.f);
    sv[2] = fmaxf(sa.z, 0.f); sv[3] = fmaxf(sa.w, 0.f);
    sv[4] = fmaxf(sb.x, 0.f); sv[5] = fmaxf(sb.y, 0.f);
    sv[6] = fmaxf(sb.z, 0.f); sv[7] = fmaxf(sb.w, 0.f);
    float ps = 0.f;
#pragma unroll
    for (int i = 0; i < 8; ++i) ps += sv[i] * sv[i];
#pragma unroll
    for (int off = 1; off < 16; off <<= 1) ps += __shfl_xor(ps, off, 16);
    if ((tid & 15) == 0) ssqs[srow] = ps;
  } else {
    const int wv2 = wv - 4;
#pragma unroll
    for (int kt = 0; kt < 128; kt += 32) {
      ushort4 alo = *(const ushort4*)&pooled[r15][kt + 4 * g];
      ushort4 ahi = *(const ushort4*)&pooled[r15][kt + 16 + 4 * g];
      short8v a;
      a[0] = alo.x; a[1] = alo.y; a[2] = alo.z; a[3] = alo.w;
      a[4] = ahi.x; a[5] = ahi.y; a[6] = ahi.z; a[7] = ahi.w;
#pragma unroll
      for (int f = 0; f < 2; ++f) {
        uint4 bw = *((const uint4*)(tWn1 + (size_t)((kt >> 5) * 8 + 2 * wv2 + f) * 512) + lane);
        qacc[f] = __builtin_amdgcn_mfma_f32_16x16x32_bf16(a, __builtin_bit_cast(short8v, bw), qacc[f], 0, 0, 0);
      }
    }
#pragma unroll
    for (int f = 0; f < 2; ++f) {
      float bv = bn1[(2 * wv2 + f) * 16 + r15];
#pragma unroll
      for (int rr = 0; rr < 4; ++rr) qacc[f][rr] = fmaxf(qacc[f][rr] + bv, 0.f);
    }
#pragma unroll
    for (int rr = 0; rr < 4; ++rr) {
      float ps = qacc[0][rr] * qacc[0][rr] + qacc[1][rr] * qacc[1][rr];
#pragma unroll
      for (int off = 1; off < 16; off <<= 1) ps += __shfl_xor(ps, off, 16);
      if (r15 == 0) ssqw[wv2][4 * g + rr] = ps;
    }
  }
  __syncthreads();

  if (tid < 256) {
    float tot = ssqs[srow] + ssqw[0][srow] + ssqw[1][srow] + ssqw[2][srow] + ssqw[3][srow];
    float sc = 1.f / fmaxf(sqrtf(tot), 1e-12f);
    float* op = out + (size_t)(r0 + srow) * 256 + sc8;
    *(float4*)op = make_float4(sv[0] * sc, sv[1] * sc, sv[2] * sc, sv[3] * sc);
    *(float4*)(op + 4) = make_float4(sv[4] * sc, sv[5] * sc, sv[6] * sc, sv[7] * sc);
  } else {
    const int wv2 = wv - 4;
#pragma unroll
    for (int rr = 0; rr < 4; ++rr) {
      int row = 4 * g + rr;
      float tot = ssqs[row] + ssqw[0][row] + ssqw[1][row] + ssqw[2][row] + ssqw[3][row];
      float sc = 1.f / fmaxf(sqrtf(tot), 1e-12f);
#pragma unroll
      for (int f = 0; f < 2; ++f)
        out[(size_t)(r0 + row) * 256 + 128 + (2 * wv2 + f) * 16 + r15] = qacc[f][rr] * sc;
    }
  }
}

extern "C" void kernel_launch(void* const* d_in, const int* in_sizes, int n_in,
                              void* d_out, int out_size, void* d_ws, size_t ws_size,
                              hipStream_t stream) {
  (void)in_sizes; (void)n_in; (void)out_size; (void)ws_size;
  const float* x   = (const float*)d_in[0];
  const float* A   = (const float*)d_in[1];
  const float* Wp0 = (const float*)d_in[2];
  const float* bp0 = (const float*)d_in[3];
  const float* Ws0 = (const float*)d_in[4];
  const float* bs0 = (const float*)d_in[5];
  const float* Wn0 = (const float*)d_in[6];
  const float* bn0 = (const float*)d_in[7];
  const float* Wp1 = (const float*)d_in[8];
  const float* bp1 = (const float*)d_in[9];
  const float* Ws1 = (const float*)d_in[10];
  const float* bs1 = (const float*)d_in[11];
  const float* Wn1 = (const float*)d_in[12];
  const float* bn1 = (const float*)d_in[13];

  char* ws = (char*)d_ws;
  auto alloc = [&](size_t bytes) { char* p = ws; ws += (bytes + 255) & ~(size_t)255; return p; };
  unsigned short* tWn0 = (unsigned short*)alloc(128 * 128 * 2);
  unsigned short* tWp1 = (unsigned short*)alloc(256 * 128 * 2);
  unsigned short* tWs1 = (unsigned short*)alloc(256 * 128 * 2);
  unsigned short* tWn1 = (unsigned short*)alloc(128 * 128 * 2);
  unsigned short* scores0 = (unsigned short*)alloc((size_t)NN * 128 * 2);
  unsigned short* scores1 = (unsigned short*)alloc((size_t)NN * 128 * 2);
  float* outp = (float*)d_out;

  void* args[] = {
    (void*)&x, (void*)&A,
    (void*)&Wp0, (void*)&bp0, (void*)&Ws0, (void*)&bs0, (void*)&Wn0, (void*)&bn0,
    (void*)&Wp1, (void*)&bp1, (void*)&Ws1, (void*)&bs1, (void*)&Wn1, (void*)&bn1,
    (void*)&tWn0, (void*)&tWp1, (void*)&tWs1, (void*)&tWn1,
    (void*)&scores0, (void*)&scores1, (void*)&outp
  };
  hipLaunchCooperativeKernel((const void*)fused_all, dim3(NN / 16), dim3(512), args, 0, stream);
}

// Round 5
// 55.346 us; speedup vs baseline: 1.9430x; 1.9430x over previous
//
#include <hip/hip_runtime.h>

#define NN 4096
#define CAP 256
#define THRV 0.99f

typedef __attribute__((ext_vector_type(8))) short short8v;
typedef __attribute__((ext_vector_type(4))) float f32x4;

__device__ inline unsigned short f2bf(float f) {
  unsigned u = __builtin_bit_cast(unsigned, f);
  u = (u + 0x7fffu + ((u >> 16) & 1u)) >> 16;   // RNE
  return (unsigned short)u;
}
__device__ inline unsigned pkmax(unsigned a, unsigned b) {
  unsigned r;
  asm("v_pk_max_u16 %0, %1, %2" : "=v"(r) : "v"(a), "v"(b));
  return r;
}
__device__ inline uint4 max4(uint4 a, uint4 b) {
  return make_uint4(pkmax(a.x, b.x), pkmax(a.y, b.y), pkmax(a.z, b.z), pkmax(a.w, b.w));
}

// Packed fragment layout for bf16 weights: frag(ktIdx,nf) is 512 bf16 (1KB),
// lane = g*16 + (n&15) holds 8 contiguous u16: elem = (k&3) + 4*((k>>4)&1),
// g = (k>>2)&3.  One uint4/lane per MFMA B-frag.

// ============ Kernel A: A-scan (bid<4096) | L0 dual GEMM (4096..4223) | prep ====
__global__ __launch_bounds__(256) void kA(
    const float* __restrict__ x, const float* __restrict__ A,
    const float* __restrict__ Wp0, const float* __restrict__ bp0,
    const float* __restrict__ Ws0, const float* __restrict__ bs0,
    const float* __restrict__ Wn0, const float* __restrict__ Wp1,
    const float* __restrict__ Ws1, const float* __restrict__ Wn1,
    int* __restrict__ cnt, unsigned short* __restrict__ nbr,
    unsigned short* __restrict__ scores0, float* __restrict__ S0,
    unsigned short* __restrict__ tWn0, unsigned short* __restrict__ tWp1,
    unsigned short* __restrict__ tWs1, unsigned short* __restrict__ tWn1) {
  const int bid = blockIdx.x;
  if (bid < NN) {
    // ---- adjacency scan: one row per block, max MLP ----
    int row = bid;
    __shared__ int sc;
    __shared__ unsigned short sn[CAP];
    if (threadIdx.x == 0) sc = 0;
    __syncthreads();
    const float4* Arow = (const float4*)(A + (size_t)row * NN);
#pragma unroll
    for (int it = 0; it < 4; ++it) {
      int j4 = it * 256 + threadIdx.x;
      float4 v = Arow[j4];
      int j = j4 * 4;
      if (v.x > THRV) { int p = atomicAdd(&sc, 1); if (p < CAP) sn[p] = (unsigned short)(j); }
      if (v.y > THRV) { int p = atomicAdd(&sc, 1); if (p < CAP) sn[p] = (unsigned short)(j + 1); }
      if (v.z > THRV) { int p = atomicAdd(&sc, 1); if (p < CAP) sn[p] = (unsigned short)(j + 2); }
      if (v.w > THRV) { int p = atomicAdd(&sc, 1); if (p < CAP) sn[p] = (unsigned short)(j + 3); }
    }
    __syncthreads();
    int c = min(sc, CAP);
    if (threadIdx.x == 0) cnt[row] = c;
    for (int k = threadIdx.x; k < c; k += 256) nbr[(size_t)row * CAP + k] = sn[k];
    return;
  }
  if (bid < NN + 128) {
    // ---- L0 dual GEMM: 128 blocks x 4 waves = 512 units = 2 sets x 256 row-blocks
    const int wv = threadIdx.x >> 6, lane = threadIdx.x & 63;
    const int unit = (bid - NN) * 4 + wv;
    const int set = unit >> 8;
    const int rb = unit & 255;
    const float* W = set ? Ws0 : Wp0;
    const float* bias = set ? bs0 : bp0;
    const int g = lane >> 4, r15 = lane & 15;
    const int row = rb * 16 + r15;
    f32x4 acc[8] = {};
    for (int kt = 0; kt < 256; kt += 32) {
      const float* xp = x + (size_t)row * 256 + kt + 4 * g;
      float4 lo = *(const float4*)xp;
      float4 hi = *(const float4*)(xp + 16);
      short8v a;
      a[0] = (short)f2bf(lo.x); a[1] = (short)f2bf(lo.y);
      a[2] = (short)f2bf(lo.z); a[3] = (short)f2bf(lo.w);
      a[4] = (short)f2bf(hi.x); a[5] = (short)f2bf(hi.y);
      a[6] = (short)f2bf(hi.z); a[7] = (short)f2bf(hi.w);
#pragma unroll
      for (int nf = 0; nf < 8; ++nf) {
        const float* wp = W + (size_t)(kt + 4 * g) * 128 + nf * 16 + r15;
        short8v b;
#pragma unroll
        for (int j = 0; j < 4; ++j) b[j] = (short)f2bf(wp[(size_t)j * 128]);
#pragma unroll
        for (int j = 0; j < 4; ++j) b[4 + j] = (short)f2bf(wp[(size_t)(16 + j) * 128]);
        acc[nf] = __builtin_amdgcn_mfma_f32_16x16x32_bf16(a, b, acc[nf], 0, 0, 0);
      }
    }
#pragma unroll
    for (int nf = 0; nf < 8; ++nf) {
      int col = nf * 16 + r15;
      float bv = bias[col];
#pragma unroll
      for (int r = 0; r < 4; ++r) {
        int orow = rb * 16 + 4 * g + r;
        float t = acc[nf][r] + bv;
        if (set == 0) scores0[(size_t)orow * 128 + col] = f2bf(fmaxf(t, 0.f));
        else          S0[(size_t)orow * 128 + col] = t;
      }
    }
    return;
  }
  // ---- weight prep into packed-fragment bf16 layout (96 blocks) ----
  int id = bid - NN - 128;
  const float* src; unsigned short* dst; int base;
  if (id < 16)      { src = Wn0; dst = tWn0; base = id; }
  else if (id < 48) { src = Wp1; dst = tWp1; base = id - 16; }
  else if (id < 80) { src = Ws1; dst = tWs1; base = id - 48; }
  else              { src = Wn1; dst = tWn1; base = id - 80; }
  int e0 = base * 1024 + threadIdx.x * 4;
  float4 v = *(const float4*)(src + e0);
  int k = e0 >> 7, n = e0 & 127;
  float vv[4] = {v.x, v.y, v.z, v.w};
  int elem = (k & 3) + 4 * ((k >> 4) & 1);
  int gg = (k >> 2) & 3;
  int fragkt = (k >> 5) * 8;
#pragma unroll
  for (int i = 0; i < 4; ++i) {
    int nn = n + i;
    int idx = ((fragkt + (nn >> 4)) << 9) + ((gg * 16 + (nn & 15)) << 3) + elem;
    dst[idx] = f2bf(vv[i]);
  }
}

// ====== fused per-16-row block (512 thr): gather(ILP8) -> pool GEMM || self ->
// ======   norm -> [L0: layer-1 dual GEMM to global] / [L1: write out] ==========
template<int LAYER>
__global__ __launch_bounds__(512) void fusedL(
    const int* __restrict__ cnt, const unsigned short* __restrict__ nbr,
    const unsigned short* __restrict__ scores_in, const float* __restrict__ S_in,
    const unsigned short* __restrict__ tWn, const float* __restrict__ bn,
    const unsigned short* __restrict__ tWp, const float* __restrict__ bp,
    const unsigned short* __restrict__ tWs, const float* __restrict__ bs,
    unsigned short* __restrict__ scores_out, float* __restrict__ S_out,
    float* __restrict__ out) {
  __shared__ int scnt[16];
  __shared__ unsigned short snb[16][CAP];
  __shared__ unsigned short pool2[16][2][136];
  __shared__ unsigned short pooled[16][136];
  __shared__ unsigned short xb[16][264];
  __shared__ float ssqs[16];
  __shared__ float ssqw[4][16];

  const int tid = threadIdx.x;
  const int wv = tid >> 6, lane = tid & 63, g = lane >> 4, r15 = lane & 15;
  const int r0 = blockIdx.x * 16;

  if (tid < 16) scnt[tid] = cnt[r0 + tid];
  {
    const ushort4* src = (const ushort4*)(nbr + (size_t)r0 * CAP);
    ushort4* dst = (ushort4*)snb;
    dst[tid] = src[tid];
    dst[tid + 512] = src[tid + 512];
  }
  __syncthreads();

  // ---- gather-max: 32 thr/row, 2-way neighbor split x 4 accumulator chains ----
  {
    const int r = tid >> 5, sub = tid & 31;
    const int h = sub >> 4, c8 = (sub & 15) * 8;
    const int c = scnt[r];
    uint4 m0 = make_uint4(0, 0, 0, 0), m1 = m0, m2 = m0, m3 = m0;
    int k = h;
    for (; k + 6 < c; k += 8) {
      int j0 = snb[r][k], j1 = snb[r][k + 2], j2 = snb[r][k + 4], j3 = snb[r][k + 6];
      uint4 a0 = *(const uint4*)(scores_in + (size_t)j0 * 128 + c8);
      uint4 a1 = *(const uint4*)(scores_in + (size_t)j1 * 128 + c8);
      uint4 a2 = *(const uint4*)(scores_in + (size_t)j2 * 128 + c8);
      uint4 a3 = *(const uint4*)(scores_in + (size_t)j3 * 128 + c8);
      m0 = max4(m0, a0); m1 = max4(m1, a1); m2 = max4(m2, a2); m3 = max4(m3, a3);
    }
    for (; k < c; k += 2)
      m0 = max4(m0, *(const uint4*)(scores_in + (size_t)snb[r][k] * 128 + c8));
    *(uint4*)&pool2[r][h][c8] = max4(max4(m0, m1), max4(m2, m3));
  }
  __syncthreads();
  if (tid < 256) {
    const int r = tid >> 4, c8 = (tid & 15) * 8;
    uint4 a = *(const uint4*)&pool2[r][0][c8];
    uint4 b = *(const uint4*)&pool2[r][1][c8];
    *(uint4*)&pooled[r][c8] = max4(a, b);
  }
  __syncthreads();

  float sv[8];
  f32x4 pacc[2] = {};
  const int srow = tid >> 4, sc8 = (tid & 15) * 8;
  if (tid < 256) {
    // ---- self half from S_in + partial ssq ----
    const float* sp = S_in + (size_t)(r0 + srow) * 128 + sc8;
    float4 sa = *(const float4*)sp;
    float4 sb = *(const float4*)(sp + 4);
    sv[0] = fmaxf(sa.x, 0.f); sv[1] = fmaxf(sa.y, 0.f);
    sv[2] = fmaxf(sa.z, 0.f); sv[3] = fmaxf(sa.w, 0.f);
    sv[4] = fmaxf(sb.x, 0.f); sv[5] = fmaxf(sb.y, 0.f);
    sv[6] = fmaxf(sb.z, 0.f); sv[7] = fmaxf(sb.w, 0.f);
    float ps = 0.f;
#pragma unroll
    for (int i = 0; i < 8; ++i) ps += sv[i] * sv[i];
#pragma unroll
    for (int off = 1; off < 16; off <<= 1) ps += __shfl_xor(ps, off, 16);
    if ((tid & 15) == 0) ssqs[srow] = ps;
  } else {
    // ---- pool GEMM: pooled[16x128] @ tWn, wave wv2 owns nf {2wv2, 2wv2+1} ----
    const int wv2 = wv - 4;
#pragma unroll
    for (int kt = 0; kt < 128; kt += 32) {
      ushort4 alo = *(const ushort4*)&pooled[r15][kt + 4 * g];
      ushort4 ahi = *(const ushort4*)&pooled[r15][kt + 16 + 4 * g];
      short8v a;
      a[0] = alo.x; a[1] = alo.y; a[2] = alo.z; a[3] = alo.w;
      a[4] = ahi.x; a[5] = ahi.y; a[6] = ahi.z; a[7] = ahi.w;
#pragma unroll
      for (int f = 0; f < 2; ++f) {
        uint4 bw = *((const uint4*)(tWn + (size_t)((kt >> 5) * 8 + 2 * wv2 + f) * 512) + lane);
        pacc[f] = __builtin_amdgcn_mfma_f32_16x16x32_bf16(a, __builtin_bit_cast(short8v, bw), pacc[f], 0, 0, 0);
      }
    }
#pragma unroll
    for (int f = 0; f < 2; ++f) {
      float bv = bn[(2 * wv2 + f) * 16 + r15];
#pragma unroll
      for (int rr = 0; rr < 4; ++rr) pacc[f][rr] = fmaxf(pacc[f][rr] + bv, 0.f);
    }
#pragma unroll
    for (int rr = 0; rr < 4; ++rr) {
      float ps = pacc[0][rr] * pacc[0][rr] + pacc[1][rr] * pacc[1][rr];
#pragma unroll
      for (int off = 1; off < 16; off <<= 1) ps += __shfl_xor(ps, off, 16);
      if (r15 == 0) ssqw[wv2][4 * g + rr] = ps;
    }
  }
  __syncthreads();

  if (LAYER == 0) {
    // ---- normalize into LDS xb ----
    if (tid < 256) {
      float tot = ssqs[srow] + ssqw[0][srow] + ssqw[1][srow] + ssqw[2][srow] + ssqw[3][srow];
      float sc = 1.f / fmaxf(sqrtf(tot), 1e-12f);
      unsigned short hh[8];
#pragma unroll
      for (int i = 0; i < 8; ++i) hh[i] = f2bf(sv[i] * sc);
      uint4 wvv;
      wvv.x = (unsigned)hh[0] | ((unsigned)hh[1] << 16);
      wvv.y = (unsigned)hh[2] | ((unsigned)hh[3] << 16);
      wvv.z = (unsigned)hh[4] | ((unsigned)hh[5] << 16);
      wvv.w = (unsigned)hh[6] | ((unsigned)hh[7] << 16);
      *(uint4*)&xb[srow][sc8] = wvv;
    } else {
      const int wv2 = wv - 4;
#pragma unroll
      for (int rr = 0; rr < 4; ++rr) {
        int row = 4 * g + rr;
        float tot = ssqs[row] + ssqw[0][row] + ssqw[1][row] + ssqw[2][row] + ssqw[3][row];
        float sc = 1.f / fmaxf(sqrtf(tot), 1e-12f);
#pragma unroll
        for (int f = 0; f < 2; ++f)
          xb[row][128 + (2 * wv2 + f) * 16 + r15] = f2bf(pacc[f][rr] * sc);
      }
    }
    __syncthreads();
    // ---- layer-1 dual GEMM on xb[16][256]: 8 waves x 2 frags ----
    const int s = wv >> 2;
    const unsigned short* Wt = s ? tWs : tWp;
    const float* bb = s ? bs : bp;
    const int nf0 = (wv & 3) * 2;
    f32x4 dacc[2] = {};
#pragma unroll
    for (int kt = 0; kt < 256; kt += 32) {
      ushort4 alo = *(const ushort4*)&xb[r15][kt + 4 * g];
      ushort4 ahi = *(const ushort4*)&xb[r15][kt + 16 + 4 * g];
      short8v a;
      a[0] = alo.x; a[1] = alo.y; a[2] = alo.z; a[3] = alo.w;
      a[4] = ahi.x; a[5] = ahi.y; a[6] = ahi.z; a[7] = ahi.w;
#pragma unroll
      for (int f = 0; f < 2; ++f) {
        uint4 bw = *((const uint4*)(Wt + (size_t)((kt >> 5) * 8 + nf0 + f) * 512) + lane);
        dacc[f] = __builtin_amdgcn_mfma_f32_16x16x32_bf16(a, __builtin_bit_cast(short8v, bw), dacc[f], 0, 0, 0);
      }
    }
#pragma unroll
    for (int f = 0; f < 2; ++f) {
      int col = (nf0 + f) * 16 + r15;
      float bv = bb[col];
#pragma unroll
      for (int rr = 0; rr < 4; ++rr) {
        int grow = r0 + 4 * g + rr;
        float t = dacc[f][rr] + bv;
        if (s == 0) scores_out[(size_t)grow * 128 + col] = f2bf(fmaxf(t, 0.f));
        else        S_out[(size_t)grow * 128 + col] = t;
      }
    }
  } else {
    // ---- normalize straight to output ----
    if (tid < 256) {
      float tot = ssqs[srow] + ssqw[0][srow] + ssqw[1][srow] + ssqw[2][srow] + ssqw[3][srow];
      float sc = 1.f / fmaxf(sqrtf(tot), 1e-12f);
      float* op = out + (size_t)(r0 + srow) * 256 + sc8;
      *(float4*)op = make_float4(sv[0] * sc, sv[1] * sc, sv[2] * sc, sv[3] * sc);
      *(float4*)(op + 4) = make_float4(sv[4] * sc, sv[5] * sc, sv[6] * sc, sv[7] * sc);
    } else {
      const int wv2 = wv - 4;
#pragma unroll
      for (int rr = 0; rr < 4; ++rr) {
        int row = 4 * g + rr;
        float tot = ssqs[row] + ssqw[0][row] + ssqw[1][row] + ssqw[2][row] + ssqw[3][row];
        float sc = 1.f / fmaxf(sqrtf(tot), 1e-12f);
#pragma unroll
        for (int f = 0; f < 2; ++f)
          out[(size_t)(r0 + row) * 256 + 128 + (2 * wv2 + f) * 16 + r15] = pacc[f][rr] * sc;
      }
    }
  }
}

extern "C" void kernel_launch(void* const* d_in, const int* in_sizes, int n_in,
                              void* d_out, int out_size, void* d_ws, size_t ws_size,
                              hipStream_t stream) {
  (void)in_sizes; (void)n_in; (void)out_size; (void)ws_size;
  const float* x   = (const float*)d_in[0];
  const float* A   = (const float*)d_in[1];
  const float* Wp0 = (const float*)d_in[2];
  const float* bp0 = (const float*)d_in[3];
  const float* Ws0 = (const float*)d_in[4];
  const float* bs0 = (const float*)d_in[5];
  const float* Wn0 = (const float*)d_in[6];
  const float* bn0 = (const float*)d_in[7];
  const float* Wp1 = (const float*)d_in[8];
  const float* bp1 = (const float*)d_in[9];
  const float* Ws1 = (const float*)d_in[10];
  const float* bs1 = (const float*)d_in[11];
  const float* Wn1 = (const float*)d_in[12];
  const float* bn1 = (const float*)d_in[13];

  char* ws = (char*)d_ws;
  auto alloc = [&](size_t bytes) { char* p = ws; ws += (bytes + 255) & ~(size_t)255; return p; };
  int* cnt             = (int*)alloc((size_t)NN * 4);
  unsigned short* nbr  = (unsigned short*)alloc((size_t)NN * CAP * 2);
  unsigned short* tWn0 = (unsigned short*)alloc(128 * 128 * 2);
  unsigned short* tWp1 = (unsigned short*)alloc(256 * 128 * 2);
  unsigned short* tWs1 = (unsigned short*)alloc(256 * 128 * 2);
  unsigned short* tWn1 = (unsigned short*)alloc(128 * 128 * 2);
  unsigned short* scores0 = (unsigned short*)alloc((size_t)NN * 128 * 2);
  unsigned short* scores1 = (unsigned short*)alloc((size_t)NN * 128 * 2);
  float* S0            = (float*)alloc((size_t)NN * 128 * 4);
  float* S1            = (float*)alloc((size_t)NN * 128 * 4);

  kA<<<NN + 128 + 96, 256, 0, stream>>>(x, A, Wp0, bp0, Ws0, bs0,
                                        Wn0, Wp1, Ws1, Wn1,
                                        cnt, nbr, scores0, S0,
                                        tWn0, tWp1, tWs1, tWn1);
  fusedL<0><<<NN / 16, 512, 0, stream>>>(cnt, nbr, scores0, S0,
                                         tWn0, bn0, tWp1, bp1, tWs1, bs1,
                                         scores1, S1, nullptr);
  fusedL<1><<<NN / 16, 512, 0, stream>>>(cnt, nbr, scores1, S1,
                                         tWn1, bn1, nullptr, nullptr, nullptr, nullptr,
                                         nullptr, nullptr, (float*)d_out);
}

// Round 7
// 51.599 us; speedup vs baseline: 2.0841x; 1.0726x over previous
//
#include <hip/hip_runtime.h>

#define NN 4096
#define CAP 256
#define THRV 0.99f

typedef __attribute__((ext_vector_type(8))) short short8v;
typedef __attribute__((ext_vector_type(4))) float f32x4;

__device__ inline unsigned short f2bf(float f) {
  unsigned u = __builtin_bit_cast(unsigned, f);
  u = (u + 0x7fffu + ((u >> 16) & 1u)) >> 16;   // RNE
  return (unsigned short)u;
}
__device__ inline unsigned pkmax(unsigned a, unsigned b) {
  unsigned r;
  asm("v_pk_max_u16 %0, %1, %2" : "=v"(r) : "v"(a), "v"(b));
  return r;
}
__device__ inline uint4 max4(uint4 a, uint4 b) {
  return make_uint4(pkmax(a.x, b.x), pkmax(a.y, b.y), pkmax(a.z, b.z), pkmax(a.w, b.w));
}

// Packed fragment layout for bf16 weights: frag(ktIdx,nf) is 512 bf16 (1KB),
// lane = g*16 + (n&15) holds 8 contiguous u16: elem = (k&3) + 4*((k>>4)&1),
// g = (k>>2)&3.  One uint4/lane per MFMA B-frag.

#define GEMM_BLKS 128
#define PREP_BLKS 96
#define SCAN_BLKS 512   // 8 rows each

// ============ Kernel A: [0,128) L0 dual GEMM | [128,224) prep | [224,736) scan ====
__global__ __launch_bounds__(256) void kA(
    const float* __restrict__ x, const float* __restrict__ A,
    const float* __restrict__ Wp0, const float* __restrict__ bp0,
    const float* __restrict__ Ws0, const float* __restrict__ bs0,
    const float* __restrict__ Wn0, const float* __restrict__ Wp1,
    const float* __restrict__ Ws1, const float* __restrict__ Wn1,
    int* __restrict__ cnt, unsigned short* __restrict__ nbr,
    unsigned short* __restrict__ scores0, float* __restrict__ S0,
    unsigned short* __restrict__ tWn0, unsigned short* __restrict__ tWp1,
    unsigned short* __restrict__ tWs1, unsigned short* __restrict__ tWn1) {
  const int bid = blockIdx.x;
  if (bid < GEMM_BLKS) {
    // ---- L0 dual GEMM: 128 blocks x 4 waves = 512 units = 2 sets x 256 row-blocks
    const int wv = threadIdx.x >> 6, lane = threadIdx.x & 63;
    const int unit = bid * 4 + wv;
    const int set = unit >> 8;
    const int rb = unit & 255;
    const float* W = set ? Ws0 : Wp0;
    const float* bias = set ? bs0 : bp0;
    const int g = lane >> 4, r15 = lane & 15;
    const int row = rb * 16 + r15;
    f32x4 acc[8] = {};
    for (int kt = 0; kt < 256; kt += 32) {
      const float* xp = x + (size_t)row * 256 + kt + 4 * g;
      float4 lo = *(const float4*)xp;
      float4 hi = *(const float4*)(xp + 16);
      short8v a;
      a[0] = (short)f2bf(lo.x); a[1] = (short)f2bf(lo.y);
      a[2] = (short)f2bf(lo.z); a[3] = (short)f2bf(lo.w);
      a[4] = (short)f2bf(hi.x); a[5] = (short)f2bf(hi.y);
      a[6] = (short)f2bf(hi.z); a[7] = (short)f2bf(hi.w);
#pragma unroll
      for (int nf = 0; nf < 8; ++nf) {
        const float* wp = W + (size_t)(kt + 4 * g) * 128 + nf * 16 + r15;
        short8v b;
#pragma unroll
        for (int j = 0; j < 4; ++j) b[j] = (short)f2bf(wp[(size_t)j * 128]);
#pragma unroll
        for (int j = 0; j < 4; ++j) b[4 + j] = (short)f2bf(wp[(size_t)(16 + j) * 128]);
        acc[nf] = __builtin_amdgcn_mfma_f32_16x16x32_bf16(a, b, acc[nf], 0, 0, 0);
      }
    }
#pragma unroll
    for (int nf = 0; nf < 8; ++nf) {
      int col = nf * 16 + r15;
      float bv = bias[col];
#pragma unroll
      for (int r = 0; r < 4; ++r) {
        int orow = rb * 16 + 4 * g + r;
        float t = acc[nf][r] + bv;
        if (set == 0) scores0[(size_t)orow * 128 + col] = f2bf(fmaxf(t, 0.f));
        else          S0[(size_t)orow * 128 + col] = t;
      }
    }
    return;
  }
  if (bid < GEMM_BLKS + PREP_BLKS) {
    // ---- weight prep into packed-fragment bf16 layout (96 blocks) ----
    int id = bid - GEMM_BLKS;
    const float* src; unsigned short* dst; int base;
    if (id < 16)      { src = Wn0; dst = tWn0; base = id; }
    else if (id < 48) { src = Wp1; dst = tWp1; base = id - 16; }
    else if (id < 80) { src = Ws1; dst = tWs1; base = id - 48; }
    else              { src = Wn1; dst = tWn1; base = id - 80; }
    int e0 = base * 1024 + threadIdx.x * 4;
    float4 v = *(const float4*)(src + e0);
    int k = e0 >> 7, n = e0 & 127;
    float vv[4] = {v.x, v.y, v.z, v.w};
    int elem = (k & 3) + 4 * ((k >> 4) & 1);
    int gg = (k >> 2) & 3;
    int fragkt = (k >> 5) * 8;
#pragma unroll
    for (int i = 0; i < 4; ++i) {
      int nn = n + i;
      int idx = ((fragkt + (nn >> 4)) << 9) + ((gg * 16 + (nn & 15)) << 3) + elem;
      dst[idx] = f2bf(vv[i]);
    }
    return;
  }
  // ---- adjacency scan: 512 persistent blocks x 8 rows, pipelined, branchless ----
  {
    __shared__ int scnt[8];
    __shared__ unsigned short snb[8][CAP];
    const int t = threadIdx.x;
    const int lane = t & 63;
    const int r0 = (bid - GEMM_BLKS - PREP_BLKS) * 8;
    if (t < 8) scnt[t] = 0;
    __syncthreads();
    // thread t owns scalar cols 16t..16t+15 of each row (4 contiguous float4)
    const float4* base = (const float4*)(A + (size_t)r0 * NN) + 4 * t;
    float4 c0 = base[0], c1 = base[1], c2 = base[2], c3 = base[3];
    for (int r = 0; r < 8; ++r) {
      float4 n0 = c0, n1 = c1, n2 = c2, n3 = c3;
      if (r < 7) {
        const float4* nb = base + (size_t)(r + 1) * (NN / 4);
        n0 = nb[0]; n1 = nb[1]; n2 = nb[2]; n3 = nb[3];
      }
      unsigned m = 0;
      m |= (c0.x > THRV) ? 0x1u : 0u;    m |= (c0.y > THRV) ? 0x2u : 0u;
      m |= (c0.z > THRV) ? 0x4u : 0u;    m |= (c0.w > THRV) ? 0x8u : 0u;
      m |= (c1.x > THRV) ? 0x10u : 0u;   m |= (c1.y > THRV) ? 0x20u : 0u;
      m |= (c1.z > THRV) ? 0x40u : 0u;   m |= (c1.w > THRV) ? 0x80u : 0u;
      m |= (c2.x > THRV) ? 0x100u : 0u;  m |= (c2.y > THRV) ? 0x200u : 0u;
      m |= (c2.z > THRV) ? 0x400u : 0u;  m |= (c2.w > THRV) ? 0x800u : 0u;
      m |= (c3.x > THRV) ? 0x1000u : 0u; m |= (c3.y > THRV) ? 0x2000u : 0u;
      m |= (c3.z > THRV) ? 0x4000u : 0u; m |= (c3.w > THRV) ? 0x8000u : 0u;
      int cntT = __popc(m);
      // wave-wide inclusive prefix scan of cntT
      int inc = cntT;
#pragma unroll
      for (int off = 1; off < 64; off <<= 1) {
        int o = __shfl_up(inc, off, 64);
        if (lane >= off) inc += o;
      }
      int excl = inc - cntT;
      int wtot = __shfl(inc, 63, 64);
      int wbase = 0;
      if (lane == 0) wbase = atomicAdd(&scnt[r], wtot);
      wbase = __shfl(wbase, 0, 64);
      int pos = wbase + excl;
      while (m) {
        int i = __ffs(m) - 1;
        m &= m - 1;
        if (pos < CAP) snb[r][pos] = (unsigned short)(16 * t + i);
        ++pos;
      }
      c0 = n0; c1 = n1; c2 = n2; c3 = n3;
    }
    __syncthreads();
    if (t < 8) cnt[r0 + t] = min(scnt[t], CAP);
    // snb is 8*CAP = 2048 u16 = 512 ushort4; 256 threads -> copy TWO each (R6 bug: copied one)
    {
      ushort4* dst = (ushort4*)(nbr + (size_t)r0 * CAP);
      const ushort4* s = (const ushort4*)snb;
      dst[t] = s[t];
      dst[t + 256] = s[t + 256];
    }
  }
}

// ====== fused per-16-row block (512 thr): gather(ILP8) -> pool GEMM || self ->
// ======   norm -> [L0: layer-1 dual GEMM to global] / [L1: write out] ==========
template<int LAYER>
__global__ __launch_bounds__(512) void fusedL(
    const int* __restrict__ cnt, const unsigned short* __restrict__ nbr,
    const unsigned short* __restrict__ scores_in, const float* __restrict__ S_in,
    const unsigned short* __restrict__ tWn, const float* __restrict__ bn,
    const unsigned short* __restrict__ tWp, const float* __restrict__ bp,
    const unsigned short* __restrict__ tWs, const float* __restrict__ bs,
    unsigned short* __restrict__ scores_out, float* __restrict__ S_out,
    float* __restrict__ out) {
  __shared__ int scnt[16];
  __shared__ unsigned short snb[16][CAP];
  __shared__ unsigned short pool2[16][2][136];
  __shared__ unsigned short pooled[16][136];
  __shared__ unsigned short xb[16][264];
  __shared__ float ssqs[16];
  __shared__ float ssqw[4][16];

  const int tid = threadIdx.x;
  const int wv = tid >> 6, lane = tid & 63, g = lane >> 4, r15 = lane & 15;
  const int r0 = blockIdx.x * 16;

  if (tid < 16) scnt[tid] = cnt[r0 + tid];
  {
    const ushort4* src = (const ushort4*)(nbr + (size_t)r0 * CAP);
    ushort4* dst = (ushort4*)snb;
    dst[tid] = src[tid];
    dst[tid + 512] = src[tid + 512];
  }
  __syncthreads();

  // ---- gather-max: 32 thr/row, 2-way neighbor split x 4 accumulator chains ----
  {
    const int r = tid >> 5, sub = tid & 31;
    const int h = sub >> 4, c8 = (sub & 15) * 8;
    const int c = scnt[r];
    uint4 m0 = make_uint4(0, 0, 0, 0), m1 = m0, m2 = m0, m3 = m0;
    int k = h;
    for (; k + 6 < c; k += 8) {
      int j0 = snb[r][k], j1 = snb[r][k + 2], j2 = snb[r][k + 4], j3 = snb[r][k + 6];
      uint4 a0 = *(const uint4*)(scores_in + (size_t)j0 * 128 + c8);
      uint4 a1 = *(const uint4*)(scores_in + (size_t)j1 * 128 + c8);
      uint4 a2 = *(const uint4*)(scores_in + (size_t)j2 * 128 + c8);
      uint4 a3 = *(const uint4*)(scores_in + (size_t)j3 * 128 + c8);
      m0 = max4(m0, a0); m1 = max4(m1, a1); m2 = max4(m2, a2); m3 = max4(m3, a3);
    }
    for (; k < c; k += 2)
      m0 = max4(m0, *(const uint4*)(scores_in + (size_t)snb[r][k] * 128 + c8));
    *(uint4*)&pool2[r][h][c8] = max4(max4(m0, m1), max4(m2, m3));
  }
  __syncthreads();
  if (tid < 256) {
    const int r = tid >> 4, c8 = (tid & 15) * 8;
    uint4 a = *(const uint4*)&pool2[r][0][c8];
    uint4 b = *(const uint4*)&pool2[r][1][c8];
    *(uint4*)&pooled[r][c8] = max4(a, b);
  }
  __syncthreads();

  float sv[8];
  f32x4 pacc[2] = {};
  const int srow = tid >> 4, sc8 = (tid & 15) * 8;
  if (tid < 256) {
    // ---- self half from S_in + partial ssq ----
    const float* sp = S_in + (size_t)(r0 + srow) * 128 + sc8;
    float4 sa = *(const float4*)sp;
    float4 sb = *(const float4*)(sp + 4);
    sv[0] = fmaxf(sa.x, 0.f); sv[1] = fmaxf(sa.y, 0.f);
    sv[2] = fmaxf(sa.z, 0.f); sv[3] = fmaxf(sa.w, 0.f);
    sv[4] = fmaxf(sb.x, 0.f); sv[5] = fmaxf(sb.y, 0.f);
    sv[6] = fmaxf(sb.z, 0.f); sv[7] = fmaxf(sb.w, 0.f);
    float ps = 0.f;
#pragma unroll
    for (int i = 0; i < 8; ++i) ps += sv[i] * sv[i];
#pragma unroll
    for (int off = 1; off < 16; off <<= 1) ps += __shfl_xor(ps, off, 16);
    if ((tid & 15) == 0) ssqs[srow] = ps;
  } else {
    // ---- pool GEMM: pooled[16x128] @ tWn, wave wv2 owns nf {2wv2, 2wv2+1} ----
    const int wv2 = wv - 4;
#pragma unroll
    for (int kt = 0; kt < 128; kt += 32) {
      ushort4 alo = *(const ushort4*)&pooled[r15][kt + 4 * g];
      ushort4 ahi = *(const ushort4*)&pooled[r15][kt + 16 + 4 * g];
      short8v a;
      a[0] = alo.x; a[1] = alo.y; a[2] = alo.z; a[3] = alo.w;
      a[4] = ahi.x; a[5] = ahi.y; a[6] = ahi.z; a[7] = ahi.w;
#pragma unroll
      for (int f = 0; f < 2; ++f) {
        uint4 bw = *((const uint4*)(tWn + (size_t)((kt >> 5) * 8 + 2 * wv2 + f) * 512) + lane);
        pacc[f] = __builtin_amdgcn_mfma_f32_16x16x32_bf16(a, __builtin_bit_cast(short8v, bw), pacc[f], 0, 0, 0);
      }
    }
#pragma unroll
    for (int f = 0; f < 2; ++f) {
      float bv = bn[(2 * wv2 + f) * 16 + r15];
#pragma unroll
      for (int rr = 0; rr < 4; ++rr) pacc[f][rr] = fmaxf(pacc[f][rr] + bv, 0.f);
    }
#pragma unroll
    for (int rr = 0; rr < 4; ++rr) {
      float ps = pacc[0][rr] * pacc[0][rr] + pacc[1][rr] * pacc[1][rr];
#pragma unroll
      for (int off = 1; off < 16; off <<= 1) ps += __shfl_xor(ps, off, 16);
      if (r15 == 0) ssqw[wv2][4 * g + rr] = ps;
    }
  }
  __syncthreads();

  if (LAYER == 0) {
    // ---- normalize into LDS xb ----
    if (tid < 256) {
      float tot = ssqs[srow] + ssqw[0][srow] + ssqw[1][srow] + ssqw[2][srow] + ssqw[3][srow];
      float sc = 1.f / fmaxf(sqrtf(tot), 1e-12f);
      unsigned short hh[8];
#pragma unroll
      for (int i = 0; i < 8; ++i) hh[i] = f2bf(sv[i] * sc);
      uint4 wvv;
      wvv.x = (unsigned)hh[0] | ((unsigned)hh[1] << 16);
      wvv.y = (unsigned)hh[2] | ((unsigned)hh[3] << 16);
      wvv.z = (unsigned)hh[4] | ((unsigned)hh[5] << 16);
      wvv.w = (unsigned)hh[6] | ((unsigned)hh[7] << 16);
      *(uint4*)&xb[srow][sc8] = wvv;
    } else {
      const int wv2 = wv - 4;
#pragma unroll
      for (int rr = 0; rr < 4; ++rr) {
        int row = 4 * g + rr;
        float tot = ssqs[row] + ssqw[0][row] + ssqw[1][row] + ssqw[2][row] + ssqw[3][row];
        float sc = 1.f / fmaxf(sqrtf(tot), 1e-12f);
#pragma unroll
        for (int f = 0; f < 2; ++f)
          xb[row][128 + (2 * wv2 + f) * 16 + r15] = f2bf(pacc[f][rr] * sc);
      }
    }
    __syncthreads();
    // ---- layer-1 dual GEMM on xb[16][256]: 8 waves x 2 frags ----
    const int s = wv >> 2;
    const unsigned short* Wt = s ? tWs : tWp;
    const float* bb = s ? bs : bp;
    const int nf0 = (wv & 3) * 2;
    f32x4 dacc[2] = {};
#pragma unroll
    for (int kt = 0; kt < 256; kt += 32) {
      ushort4 alo = *(const ushort4*)&xb[r15][kt + 4 * g];
      ushort4 ahi = *(const ushort4*)&xb[r15][kt + 16 + 4 * g];
      short8v a;
      a[0] = alo.x; a[1] = alo.y; a[2] = alo.z; a[3] = alo.w;
      a[4] = ahi.x; a[5] = ahi.y; a[6] = ahi.z; a[7] = ahi.w;
#pragma unroll
      for (int f = 0; f < 2; ++f) {
        uint4 bw = *((const uint4*)(Wt + (size_t)((kt >> 5) * 8 + nf0 + f) * 512) + lane);
        dacc[f] = __builtin_amdgcn_mfma_f32_16x16x32_bf16(a, __builtin_bit_cast(short8v, bw), dacc[f], 0, 0, 0);
      }
    }
#pragma unroll
    for (int f = 0; f < 2; ++f) {
      int col = (nf0 + f) * 16 + r15;
      float bv = bb[col];
#pragma unroll
      for (int rr = 0; rr < 4; ++rr) {
        int grow = r0 + 4 * g + rr;
        float t = dacc[f][rr] + bv;
        if (s == 0) scores_out[(size_t)grow * 128 + col] = f2bf(fmaxf(t, 0.f));
        else        S_out[(size_t)grow * 128 + col] = t;
      }
    }
  } else {
    // ---- normalize straight to output ----
    if (tid < 256) {
      float tot = ssqs[srow] + ssqw[0][srow] + ssqw[1][srow] + ssqw[2][srow] + ssqw[3][srow];
      float sc = 1.f / fmaxf(sqrtf(tot), 1e-12f);
      float* op = out + (size_t)(r0 + srow) * 256 + sc8;
      *(float4*)op = make_float4(sv[0] * sc, sv[1] * sc, sv[2] * sc, sv[3] * sc);
      *(float4*)(op + 4) = make_float4(sv[4] * sc, sv[5] * sc, sv[6] * sc, sv[7] * sc);
    } else {
      const int wv2 = wv - 4;
#pragma unroll
      for (int rr = 0; rr < 4; ++rr) {
        int row = 4 * g + rr;
        float tot = ssqs[row] + ssqw[0][row] + ssqw[1][row] + ssqw[2][row] + ssqw[3][row];
        float sc = 1.f / fmaxf(sqrtf(tot), 1e-12f);
#pragma unroll
        for (int f = 0; f < 2; ++f)
          out[(size_t)(r0 + row) * 256 + 128 + (2 * wv2 + f) * 16 + r15] = pacc[f][rr] * sc;
      }
    }
  }
}

extern "C" void kernel_launch(void* const* d_in, const int* in_sizes, int n_in,
                              void* d_out, int out_size, void* d_ws, size_t ws_size,
                              hipStream_t stream) {
  (void)in_sizes; (void)n_in; (void)out_size; (void)ws_size;
  const float* x   = (const float*)d_in[0];
  const float* A   = (const float*)d_in[1];
  const float* Wp0 = (const float*)d_in[2];
  const float* bp0 = (const float*)d_in[3];
  const float* Ws0 = (const float*)d_in[4];
  const float* bs0 = (const float*)d_in[5];
  const float* Wn0 = (const float*)d_in[6];
  const float* bn0 = (const float*)d_in[7];
  const float* Wp1 = (const float*)d_in[8];
  const float* bp1 = (const float*)d_in[9];
  const float* Ws1 = (const float*)d_in[10];
  const float* bs1 = (const float*)d_in[11];
  const float* Wn1 = (const float*)d_in[12];
  const float* bn1 = (const float*)d_in[13];

  char* ws = (char*)d_ws;
  auto alloc = [&](size_t bytes) { char* p = ws; ws += (bytes + 255) & ~(size_t)255; return p; };
  int* cnt             = (int*)alloc((size_t)NN * 4);
  unsigned short* nbr  = (unsigned short*)alloc((size_t)NN * CAP * 2);
  unsigned short* tWn0 = (unsigned short*)alloc(128 * 128 * 2);
  unsigned short* tWp1 = (unsigned short*)alloc(256 * 128 * 2);
  unsigned short* tWs1 = (unsigned short*)alloc(256 * 128 * 2);
  unsigned short* tWn1 = (unsigned short*)alloc(128 * 128 * 2);
  unsigned short* scores0 = (unsigned short*)alloc((size_t)NN * 128 * 2);
  unsigned short* scores1 = (unsigned short*)alloc((size_t)NN * 128 * 2);
  float* S0            = (float*)alloc((size_t)NN * 128 * 4);
  float* S1            = (float*)alloc((size_t)NN * 128 * 4);

  kA<<<GEMM_BLKS + PREP_BLKS + SCAN_BLKS, 256, 0, stream>>>(
      x, A, Wp0, bp0, Ws0, bs0, Wn0, Wp1, Ws1, Wn1,
      cnt, nbr, scores0, S0, tWn0, tWp1, tWs1, tWn1);
  fusedL<0><<<NN / 16, 512, 0, stream>>>(cnt, nbr, scores0, S0,
                                         tWn0, bn0, tWp1, bp1, tWs1, bs1,
                                         scores1, S1, nullptr);
  fusedL<1><<<NN / 16, 512, 0, stream>>>(cnt, nbr, scores1, S1,
                                         tWn1, bn1, nullptr, nullptr, nullptr, nullptr,
                                         nullptr, nullptr, (float*)d_out);
}

// Round 8
// 44.383 us; speedup vs baseline: 2.4230x; 1.1626x over previous
//
#include <hip/hip_runtime.h>

#define NN 4096
#define CAP 256
#define THRV 0.99f

typedef __attribute__((ext_vector_type(8))) short short8v;
typedef __attribute__((ext_vector_type(4))) float f32x4;

__device__ inline unsigned short f2bf(float f) {
  unsigned u = __builtin_bit_cast(unsigned, f);
  u = (u + 0x7fffu + ((u >> 16) & 1u)) >> 16;   // RNE
  return (unsigned short)u;
}
__device__ inline unsigned pkmax(unsigned a, unsigned b) {
  unsigned r;
  asm("v_pk_max_u16 %0, %1, %2" : "=v"(r) : "v"(a), "v"(b));
  return r;
}
__device__ inline uint4 max4(uint4 a, uint4 b) {
  return make_uint4(pkmax(a.x, b.x), pkmax(a.y, b.y), pkmax(a.z, b.z), pkmax(a.w, b.w));
}

// Packed fragment layout for bf16 weights: frag(ktIdx,nf) is 512 bf16 (1KB),
// lane = g*16 + (n&15) holds 8 contiguous u16: elem = (k&3) + 4*((k>>4)&1),
// g = (k>>2)&3.  One uint4 (ds_read_b128) per lane per MFMA B-frag.

#define GEMM_BLKS 128   // 2 sets x 64 blocks x 64 rows
#define PREP_BLKS 96
#define SCAN_BLKS 256   // 16 rows each

// ===== Kernel A: [0,128) L0 dual GEMM (LDS-staged W) | [128,224) prep | scan ====
__global__ __launch_bounds__(256) void kA(
    const float* __restrict__ x, const float* __restrict__ A,
    const float* __restrict__ Wp0, const float* __restrict__ bp0,
    const float* __restrict__ Ws0, const float* __restrict__ bs0,
    const float* __restrict__ Wn0, const float* __restrict__ Wp1,
    const float* __restrict__ Ws1, const float* __restrict__ Wn1,
    int* __restrict__ cnt, unsigned short* __restrict__ nbr,
    unsigned short* __restrict__ scores0, float* __restrict__ S0,
    unsigned short* __restrict__ tWn0, unsigned short* __restrict__ tWp1,
    unsigned short* __restrict__ tWs1, unsigned short* __restrict__ tWn1) {
  __shared__ union SM {
    unsigned short w[32768];                       // 64 KB staged weights (GEMM blocks)
    struct { int scnt[16]; unsigned short snb[16][CAP]; } scan;
  } sm;
  const int bid = blockIdx.x;
  const int tid = threadIdx.x;

  if (bid < GEMM_BLKS) {
    // ---- stage W(set) f32 -> packed bf16 LDS (once per block) ----
    const int set = bid >> 6;
    const float* W = set ? Ws0 : Wp0;
    const float* bias = set ? bs0 : bp0;
#pragma unroll
    for (int it = 0; it < 32; ++it) {
      int e0 = it * 1024 + tid * 4;
      float4 v = *(const float4*)(W + e0);
      int k = e0 >> 7, n = e0 & 127;
      int elem = (k & 3) + 4 * ((k >> 4) & 1);
      int gg = (k >> 2) & 3;
      int kt8 = (k >> 5) * 8;
      float vv[4] = {v.x, v.y, v.z, v.w};
#pragma unroll
      for (int i = 0; i < 4; ++i) {
        int nn = n + i;
        sm.w[((kt8 + (nn >> 4)) << 9) + ((gg * 16 + (nn & 15)) << 3) + elem] = f2bf(vv[i]);
      }
    }
    __syncthreads();
    // ---- GEMM: 4 waves x 16 rows, B-frags via ds_read_b128 ----
    const int wv = tid >> 6, lane = tid & 63;
    const int g = lane >> 4, r15 = lane & 15;
    const int rb16 = (bid & 63) * 64 + wv * 16;
    const int row = rb16 + r15;
    f32x4 acc[8] = {};
#pragma unroll
    for (int ktIdx = 0; ktIdx < 8; ++ktIdx) {
      const float* xp = x + (size_t)row * 256 + ktIdx * 32 + 4 * g;
      float4 lo = *(const float4*)xp;
      float4 hi = *(const float4*)(xp + 16);
      short8v a;
      a[0] = (short)f2bf(lo.x); a[1] = (short)f2bf(lo.y);
      a[2] = (short)f2bf(lo.z); a[3] = (short)f2bf(lo.w);
      a[4] = (short)f2bf(hi.x); a[5] = (short)f2bf(hi.y);
      a[6] = (short)f2bf(hi.z); a[7] = (short)f2bf(hi.w);
#pragma unroll
      for (int nf = 0; nf < 8; ++nf) {
        uint4 bw = *(const uint4*)(sm.w + ((ktIdx * 8 + nf) << 9) + lane * 8);
        acc[nf] = __builtin_amdgcn_mfma_f32_16x16x32_bf16(a, __builtin_bit_cast(short8v, bw), acc[nf], 0, 0, 0);
      }
    }
#pragma unroll
    for (int nf = 0; nf < 8; ++nf) {
      int col = nf * 16 + r15;
      float bv = bias[col];
#pragma unroll
      for (int r = 0; r < 4; ++r) {
        int orow = rb16 + 4 * g + r;
        float t = acc[nf][r] + bv;
        if (set == 0) scores0[(size_t)orow * 128 + col] = f2bf(fmaxf(t, 0.f));
        else          S0[(size_t)orow * 128 + col] = t;
      }
    }
    return;
  }
  if (bid < GEMM_BLKS + PREP_BLKS) {
    // ---- weight prep into packed-fragment bf16 layout (96 blocks) ----
    int id = bid - GEMM_BLKS;
    const float* src; unsigned short* dst; int base;
    if (id < 16)      { src = Wn0; dst = tWn0; base = id; }
    else if (id < 48) { src = Wp1; dst = tWp1; base = id - 16; }
    else if (id < 80) { src = Ws1; dst = tWs1; base = id - 48; }
    else              { src = Wn1; dst = tWn1; base = id - 80; }
    int e0 = base * 1024 + tid * 4;
    float4 v = *(const float4*)(src + e0);
    int k = e0 >> 7, n = e0 & 127;
    float vv[4] = {v.x, v.y, v.z, v.w};
    int elem = (k & 3) + 4 * ((k >> 4) & 1);
    int gg = (k >> 2) & 3;
    int fragkt = (k >> 5) * 8;
#pragma unroll
    for (int i = 0; i < 4; ++i) {
      int nn = n + i;
      int idx = ((fragkt + (nn >> 4)) << 9) + ((gg * 16 + (nn & 15)) << 3) + elem;
      dst[idx] = f2bf(vv[i]);
    }
    return;
  }
  // ---- adjacency scan: 256 blocks x 16 rows, pipelined, branchless compaction ----
  {
    const int t = tid;
    const int lane = t & 63;
    const int r0 = (bid - GEMM_BLKS - PREP_BLKS) * 16;
    if (t < 16) sm.scan.scnt[t] = 0;
    __syncthreads();
    // thread t owns scalar cols 16t..16t+15 of each row (4 contiguous float4)
    const float4* base = (const float4*)(A + (size_t)r0 * NN) + 4 * t;
    float4 c0 = base[0], c1 = base[1], c2 = base[2], c3 = base[3];
    for (int r = 0; r < 16; ++r) {
      float4 n0 = c0, n1 = c1, n2 = c2, n3 = c3;
      if (r < 15) {
        const float4* nb = base + (size_t)(r + 1) * (NN / 4);
        n0 = nb[0]; n1 = nb[1]; n2 = nb[2]; n3 = nb[3];
      }
      unsigned m = 0;
      m |= (c0.x > THRV) ? 0x1u : 0u;    m |= (c0.y > THRV) ? 0x2u : 0u;
      m |= (c0.z > THRV) ? 0x4u : 0u;    m |= (c0.w > THRV) ? 0x8u : 0u;
      m |= (c1.x > THRV) ? 0x10u : 0u;   m |= (c1.y > THRV) ? 0x20u : 0u;
      m |= (c1.z > THRV) ? 0x40u : 0u;   m |= (c1.w > THRV) ? 0x80u : 0u;
      m |= (c2.x > THRV) ? 0x100u : 0u;  m |= (c2.y > THRV) ? 0x200u : 0u;
      m |= (c2.z > THRV) ? 0x400u : 0u;  m |= (c2.w > THRV) ? 0x800u : 0u;
      m |= (c3.x > THRV) ? 0x1000u : 0u; m |= (c3.y > THRV) ? 0x2000u : 0u;
      m |= (c3.z > THRV) ? 0x4000u : 0u; m |= (c3.w > THRV) ? 0x8000u : 0u;
      int cntT = __popc(m);
      int inc = cntT;
#pragma unroll
      for (int off = 1; off < 64; off <<= 1) {
        int o = __shfl_up(inc, off, 64);
        if (lane >= off) inc += o;
      }
      int excl = inc - cntT;
      int wtot = __shfl(inc, 63, 64);
      int wbase = 0;
      if (lane == 0) wbase = atomicAdd(&sm.scan.scnt[r], wtot);
      wbase = __shfl(wbase, 0, 64);
      int pos = wbase + excl;
      while (m) {
        int i = __ffs(m) - 1;
        m &= m - 1;
        if (pos < CAP) sm.scan.snb[r][pos] = (unsigned short)(16 * t + i);
        ++pos;
      }
      c0 = n0; c1 = n1; c2 = n2; c3 = n3;
    }
    __syncthreads();
    if (t < 16) cnt[r0 + t] = min(sm.scan.scnt[t], CAP);
    // snb = 16*256 u16 = 1024 ushort4; 256 threads -> 4 each
    {
      ushort4* dst = (ushort4*)(nbr + (size_t)r0 * CAP);
      const ushort4* s = (const ushort4*)sm.scan.snb;
#pragma unroll
      for (int i = 0; i < 4; ++i) dst[t + 256 * i] = s[t + 256 * i];
    }
  }
}

// ====== fused per-16-row block (512 thr): gather(ILP8) -> pool GEMM || self ->
// ======   norm -> [L0: layer-1 dual GEMM to global] / [L1: write out] ==========
template<int LAYER>
__global__ __launch_bounds__(512) void fusedL(
    const int* __restrict__ cnt, const unsigned short* __restrict__ nbr,
    const unsigned short* __restrict__ scores_in, const float* __restrict__ S_in,
    const unsigned short* __restrict__ tWn, const float* __restrict__ bn,
    const unsigned short* __restrict__ tWp, const float* __restrict__ bp,
    const unsigned short* __restrict__ tWs, const float* __restrict__ bs,
    unsigned short* __restrict__ scores_out, float* __restrict__ S_out,
    float* __restrict__ out) {
  __shared__ int scnt[16];
  __shared__ unsigned short snb[16][CAP];
  __shared__ unsigned short pool2[16][2][136];
  __shared__ unsigned short pooled[16][136];
  __shared__ unsigned short xb[16][264];
  __shared__ float ssqs[16];
  __shared__ float ssqw[4][16];

  const int tid = threadIdx.x;
  const int wv = tid >> 6, lane = tid & 63, g = lane >> 4, r15 = lane & 15;
  const int r0 = blockIdx.x * 16;

  if (tid < 16) scnt[tid] = cnt[r0 + tid];
  {
    const ushort4* src = (const ushort4*)(nbr + (size_t)r0 * CAP);
    ushort4* dst = (ushort4*)snb;
    dst[tid] = src[tid];
    dst[tid + 512] = src[tid + 512];
  }
  __syncthreads();

  // ---- gather-max: 32 thr/row, 2-way neighbor split x 4 accumulator chains ----
  {
    const int r = tid >> 5, sub = tid & 31;
    const int h = sub >> 4, c8 = (sub & 15) * 8;
    const int c = scnt[r];
    uint4 m0 = make_uint4(0, 0, 0, 0), m1 = m0, m2 = m0, m3 = m0;
    int k = h;
    for (; k + 6 < c; k += 8) {
      int j0 = snb[r][k], j1 = snb[r][k + 2], j2 = snb[r][k + 4], j3 = snb[r][k + 6];
      uint4 a0 = *(const uint4*)(scores_in + (size_t)j0 * 128 + c8);
      uint4 a1 = *(const uint4*)(scores_in + (size_t)j1 * 128 + c8);
      uint4 a2 = *(const uint4*)(scores_in + (size_t)j2 * 128 + c8);
      uint4 a3 = *(const uint4*)(scores_in + (size_t)j3 * 128 + c8);
      m0 = max4(m0, a0); m1 = max4(m1, a1); m2 = max4(m2, a2); m3 = max4(m3, a3);
    }
    for (; k < c; k += 2)
      m0 = max4(m0, *(const uint4*)(scores_in + (size_t)snb[r][k] * 128 + c8));
    *(uint4*)&pool2[r][h][c8] = max4(max4(m0, m1), max4(m2, m3));
  }
  __syncthreads();
  if (tid < 256) {
    const int r = tid >> 4, c8 = (tid & 15) * 8;
    uint4 a = *(const uint4*)&pool2[r][0][c8];
    uint4 b = *(const uint4*)&pool2[r][1][c8];
    *(uint4*)&pooled[r][c8] = max4(a, b);
  }
  __syncthreads();

  float sv[8];
  f32x4 pacc[2] = {};
  const int srow = tid >> 4, sc8 = (tid & 15) * 8;
  if (tid < 256) {
    const float* sp = S_in + (size_t)(r0 + srow) * 128 + sc8;
    float4 sa = *(const float4*)sp;
    float4 sb = *(const float4*)(sp + 4);
    sv[0] = fmaxf(sa.x, 0.f); sv[1] = fmaxf(sa.y, 0.f);
    sv[2] = fmaxf(sa.z, 0.f); sv[3] = fmaxf(sa.w, 0.f);
    sv[4] = fmaxf(sb.x, 0.f); sv[5] = fmaxf(sb.y, 0.f);
    sv[6] = fmaxf(sb.z, 0.f); sv[7] = fmaxf(sb.w, 0.f);
    float ps = 0.f;
#pragma unroll
    for (int i = 0; i < 8; ++i) ps += sv[i] * sv[i];
#pragma unroll
    for (int off = 1; off < 16; off <<= 1) ps += __shfl_xor(ps, off, 16);
    if ((tid & 15) == 0) ssqs[srow] = ps;
  } else {
    const int wv2 = wv - 4;
#pragma unroll
    for (int kt = 0; kt < 128; kt += 32) {
      ushort4 alo = *(const ushort4*)&pooled[r15][kt + 4 * g];
      ushort4 ahi = *(const ushort4*)&pooled[r15][kt + 16 + 4 * g];
      short8v a;
      a[0] = alo.x; a[1] = alo.y; a[2] = alo.z; a[3] = alo.w;
      a[4] = ahi.x; a[5] = ahi.y; a[6] = ahi.z; a[7] = ahi.w;
#pragma unroll
      for (int f = 0; f < 2; ++f) {
        uint4 bw = *((const uint4*)(tWn + (size_t)((kt >> 5) * 8 + 2 * wv2 + f) * 512) + lane);
        pacc[f] = __builtin_amdgcn_mfma_f32_16x16x32_bf16(a, __builtin_bit_cast(short8v, bw), pacc[f], 0, 0, 0);
      }
    }
#pragma unroll
    for (int f = 0; f < 2; ++f) {
      float bv = bn[(2 * wv2 + f) * 16 + r15];
#pragma unroll
      for (int rr = 0; rr < 4; ++rr) pacc[f][rr] = fmaxf(pacc[f][rr] + bv, 0.f);
    }
#pragma unroll
    for (int rr = 0; rr < 4; ++rr) {
      float ps = pacc[0][rr] * pacc[0][rr] + pacc[1][rr] * pacc[1][rr];
#pragma unroll
      for (int off = 1; off < 16; off <<= 1) ps += __shfl_xor(ps, off, 16);
      if (r15 == 0) ssqw[wv2][4 * g + rr] = ps;
    }
  }
  __syncthreads();

  if (LAYER == 0) {
    if (tid < 256) {
      float tot = ssqs[srow] + ssqw[0][srow] + ssqw[1][srow] + ssqw[2][srow] + ssqw[3][srow];
      float sc = 1.f / fmaxf(sqrtf(tot), 1e-12f);
      unsigned short hh[8];
#pragma unroll
      for (int i = 0; i < 8; ++i) hh[i] = f2bf(sv[i] * sc);
      uint4 wvv;
      wvv.x = (unsigned)hh[0] | ((unsigned)hh[1] << 16);
      wvv.y = (unsigned)hh[2] | ((unsigned)hh[3] << 16);
      wvv.z = (unsigned)hh[4] | ((unsigned)hh[5] << 16);
      wvv.w = (unsigned)hh[6] | ((unsigned)hh[7] << 16);
      *(uint4*)&xb[srow][sc8] = wvv;
    } else {
      const int wv2 = wv - 4;
#pragma unroll
      for (int rr = 0; rr < 4; ++rr) {
        int row = 4 * g + rr;
        float tot = ssqs[row] + ssqw[0][row] + ssqw[1][row] + ssqw[2][row] + ssqw[3][row];
        float sc = 1.f / fmaxf(sqrtf(tot), 1e-12f);
#pragma unroll
        for (int f = 0; f < 2; ++f)
          xb[row][128 + (2 * wv2 + f) * 16 + r15] = f2bf(pacc[f][rr] * sc);
      }
    }
    __syncthreads();
    const int s = wv >> 2;
    const unsigned short* Wt = s ? tWs : tWp;
    const float* bb = s ? bs : bp;
    const int nf0 = (wv & 3) * 2;
    f32x4 dacc[2] = {};
#pragma unroll
    for (int kt = 0; kt < 256; kt += 32) {
      ushort4 alo = *(const ushort4*)&xb[r15][kt + 4 * g];
      ushort4 ahi = *(const ushort4*)&xb[r15][kt + 16 + 4 * g];
      short8v a;
      a[0] = alo.x; a[1] = alo.y; a[2] = alo.z; a[3] = alo.w;
      a[4] = ahi.x; a[5] = ahi.y; a[6] = ahi.z; a[7] = ahi.w;
#pragma unroll
      for (int f = 0; f < 2; ++f) {
        uint4 bw = *((const uint4*)(Wt + (size_t)((kt >> 5) * 8 + nf0 + f) * 512) + lane);
        dacc[f] = __builtin_amdgcn_mfma_f32_16x16x32_bf16(a, __builtin_bit_cast(short8v, bw), dacc[f], 0, 0, 0);
      }
    }
#pragma unroll
    for (int f = 0; f < 2; ++f) {
      int col = (nf0 + f) * 16 + r15;
      float bv = bb[col];
#pragma unroll
      for (int rr = 0; rr < 4; ++rr) {
        int grow = r0 + 4 * g + rr;
        float t = dacc[f][rr] + bv;
        if (s == 0) scores_out[(size_t)grow * 128 + col] = f2bf(fmaxf(t, 0.f));
        else        S_out[(size_t)grow * 128 + col] = t;
      }
    }
  } else {
    if (tid < 256) {
      float tot = ssqs[srow] + ssqw[0][srow] + ssqw[1][srow] + ssqw[2][srow] + ssqw[3][srow];
      float sc = 1.f / fmaxf(sqrtf(tot), 1e-12f);
      float* op = out + (size_t)(r0 + srow) * 256 + sc8;
      *(float4*)op = make_float4(sv[0] * sc, sv[1] * sc, sv[2] * sc, sv[3] * sc);
      *(float4*)(op + 4) = make_float4(sv[4] * sc, sv[5] * sc, sv[6] * sc, sv[7] * sc);
    } else {
      const int wv2 = wv - 4;
#pragma unroll
      for (int rr = 0; rr < 4; ++rr) {
        int row = 4 * g + rr;
        float tot = ssqs[row] + ssqw[0][row] + ssqw[1][row] + ssqw[2][row] + ssqw[3][row];
        float sc = 1.f / fmaxf(sqrtf(tot), 1e-12f);
#pragma unroll
        for (int f = 0; f < 2; ++f)
          out[(size_t)(r0 + row) * 256 + 128 + (2 * wv2 + f) * 16 + r15] = pacc[f][rr] * sc;
      }
    }
  }
}

extern "C" void kernel_launch(void* const* d_in, const int* in_sizes, int n_in,
                              void* d_out, int out_size, void* d_ws, size_t ws_size,
                              hipStream_t stream) {
  (void)in_sizes; (void)n_in; (void)out_size; (void)ws_size;
  const float* x   = (const float*)d_in[0];
  const float* A   = (const float*)d_in[1];
  const float* Wp0 = (const float*)d_in[2];
  const float* bp0 = (const float*)d_in[3];
  const float* Ws0 = (const float*)d_in[4];
  const float* bs0 = (const float*)d_in[5];
  const float* Wn0 = (const float*)d_in[6];
  const float* bn0 = (const float*)d_in[7];
  const float* Wp1 = (const float*)d_in[8];
  const float* bp1 = (const float*)d_in[9];
  const float* Ws1 = (const float*)d_in[10];
  const float* bs1 = (const float*)d_in[11];
  const float* Wn1 = (const float*)d_in[12];
  const float* bn1 = (const float*)d_in[13];

  char* ws = (char*)d_ws;
  auto alloc = [&](size_t bytes) { char* p = ws; ws += (bytes + 255) & ~(size_t)255; return p; };
  int* cnt             = (int*)alloc((size_t)NN * 4);
  unsigned short* nbr  = (unsigned short*)alloc((size_t)NN * CAP * 2);
  unsigned short* tWn0 = (unsigned short*)alloc(128 * 128 * 2);
  unsigned short* tWp1 = (unsigned short*)alloc(256 * 128 * 2);
  unsigned short* tWs1 = (unsigned short*)alloc(256 * 128 * 2);
  unsigned short* tWn1 = (unsigned short*)alloc(128 * 128 * 2);
  unsigned short* scores0 = (unsigned short*)alloc((size_t)NN * 128 * 2);
  unsigned short* scores1 = (unsigned short*)alloc((size_t)NN * 128 * 2);
  float* S0            = (float*)alloc((size_t)NN * 128 * 4);
  float* S1            = (float*)alloc((size_t)NN * 128 * 4);

  kA<<<GEMM_BLKS + PREP_BLKS + SCAN_BLKS, 256, 0, stream>>>(
      x, A, Wp0, bp0, Ws0, bs0, Wn0, Wp1, Ws1, Wn1,
      cnt, nbr, scores0, S0, tWn0, tWp1, tWs1, tWn1);
  fusedL<0><<<NN / 16, 512, 0, stream>>>(cnt, nbr, scores0, S0,
                                         tWn0, bn0, tWp1, bp1, tWs1, bs1,
                                         scores1, S1, nullptr);
  fusedL<1><<<NN / 16, 512, 0, stream>>>(cnt, nbr, scores1, S1,
                                         tWn1, bn1, nullptr, nullptr, nullptr, nullptr,
                                         nullptr, nullptr, (float*)d_out);
}